// Round 1
// baseline (541.872 us; speedup 1.0000x reference)
//
#include <hip/hip_runtime.h>
#include <math.h>

#define NB 4
#define NL 2048
#define ND 768
#define NH 12
#define NK 9
#define NIPG 64
#define NPAD 4

// ---------------------------------------------------------------------------
// Kernel 1: v[m][n] = sum_k q[m][k] * pt_w[n][k] + pt_b[n]
// M = B*L = 8192, N = D = 768, K = D = 768.  fp32 tiled 64x64, BK=32.
// ---------------------------------------------------------------------------
__global__ __launch_bounds__(256) void gemm_v(const float* __restrict__ A,
                                              const float* __restrict__ Bw,
                                              const float* __restrict__ bias,
                                              float* __restrict__ C) {
  // pad to 36 floats/row: keeps float4 alignment (144B) and rotates banks by 4
  __shared__ float As[64][36];
  __shared__ float Bs[64][36];
  const int m0 = blockIdx.x * 64;
  const int n0 = blockIdx.y * 64;
  const int t  = threadIdx.x;
  const int tx = t & 15, ty = t >> 4;   // 16x16 thread grid, 4x4 outputs each
  const int lr = t >> 3, lq = t & 7;    // loader: row, k-quad
  float acc[4][4] = {};

  for (int k0 = 0; k0 < ND; k0 += 32) {
    float4 a0 = *(const float4*)&A[(size_t)(m0 + lr) * ND + k0 + lq * 4];
    float4 a1 = *(const float4*)&A[(size_t)(m0 + lr + 32) * ND + k0 + lq * 4];
    float4 b0 = *(const float4*)&Bw[(size_t)(n0 + lr) * ND + k0 + lq * 4];
    float4 b1 = *(const float4*)&Bw[(size_t)(n0 + lr + 32) * ND + k0 + lq * 4];
    __syncthreads();   // previous iter's reads done before overwrite
    *(float4*)&As[lr][lq * 4]      = a0;
    *(float4*)&As[lr + 32][lq * 4] = a1;
    *(float4*)&Bs[lr][lq * 4]      = b0;
    *(float4*)&Bs[lr + 32][lq * 4] = b1;
    __syncthreads();
#pragma unroll
    for (int qq = 0; qq < 8; ++qq) {
      float4 av[4], bv[4];
#pragma unroll
      for (int i = 0; i < 4; ++i) av[i] = *(float4*)&As[ty * 4 + i][qq * 4];
#pragma unroll
      for (int j = 0; j < 4; ++j) bv[j] = *(float4*)&Bs[tx * 4 + j][qq * 4];
#pragma unroll
      for (int i = 0; i < 4; ++i)
#pragma unroll
        for (int j = 0; j < 4; ++j) {
          acc[i][j] = fmaf(av[i].x, bv[j].x, acc[i][j]);
          acc[i][j] = fmaf(av[i].y, bv[j].y, acc[i][j]);
          acc[i][j] = fmaf(av[i].z, bv[j].z, acc[i][j]);
          acc[i][j] = fmaf(av[i].w, bv[j].w, acc[i][j]);
        }
    }
  }
  const float bx = bias[n0 + tx * 4 + 0];
  const float by = bias[n0 + tx * 4 + 1];
  const float bz = bias[n0 + tx * 4 + 2];
  const float bw = bias[n0 + tx * 4 + 3];
#pragma unroll
  for (int i = 0; i < 4; ++i) {
    float4 o;
    o.x = acc[i][0] + bx;
    o.y = acc[i][1] + by;
    o.z = acc[i][2] + bz;
    o.w = acc[i][3] + bw;
    *(float4*)&C[(size_t)(m0 + ty * 4 + i) * ND + n0 + tx * 4] = o;
  }
}

// ---------------------------------------------------------------------------
// Kernel 2: dynamic conv weights.
// One block per (b, h, 64-l-block); 256 threads.
// dw   : depthwise conv(q, dw_w) over l (pad 4)
// pw   : per-head 64x64 mix + pw_b  -> key_conv_attn
// ca   : key_conv_attn * q
// kern : ca . ak_w[h][k][:] + ak_b  -> softmax over k -> wout (B,L,H,K)
// ---------------------------------------------------------------------------
__global__ __launch_bounds__(256) void attn_w(const float* __restrict__ q,
                                              const float* __restrict__ dw_w,
                                              const float* __restrict__ pw_w,
                                              const float* __restrict__ pw_b,
                                              const float* __restrict__ ak_w,
                                              const float* __restrict__ ak_b,
                                              float* __restrict__ wout) {
  __shared__ float qs[72][64];      // rows l0-4 .. l0+67 of head slice
  __shared__ float dws[64][65];     // dw result; reused for ca
  __shared__ float pwws[64][64];    // pw_w transposed: pwws[i][o]
  __shared__ float ks[64][13];      // kern logits
  const int l0 = blockIdx.x * 64;
  const int h  = blockIdx.y;
  const int b  = blockIdx.z;
  const int d0 = h * NIPG;
  const int t  = threadIdx.x;
  const int c  = t & 63;      // channel within head (also 'o' in pw step)
  const int rr = t >> 6;      // wave id 0..3

  // stage q slice (zero-padded at sequence edges)
  for (int r = rr; r < 72; r += 4) {
    int l = l0 - NPAD + r;
    qs[r][c] = (l >= 0 && l < NL) ? q[((size_t)(b * NL + l)) * ND + d0 + c] : 0.f;
  }
  // stage pw_w transposed (pwws[i][o] = pw_w[h][o][i]) for conflict-free reads
  for (int i = rr; i < 64; i += 4) {
    pwws[i][c] = pw_w[(size_t)(h * NIPG + c) * NIPG + i];
  }
  // depthwise taps for channel c
  float dwk[NK];
#pragma unroll
  for (int k = 0; k < NK; ++k) dwk[k] = dw_w[(size_t)(d0 + c) * NK + k];
  __syncthreads();

  // depthwise conv: each thread does 16 l-positions for its channel
  const int lset = rr * 16;
#pragma unroll
  for (int l2 = 0; l2 < 16; ++l2) {
    const int l = lset + l2;
    float s = 0.f;
#pragma unroll
    for (int k = 0; k < NK; ++k) s = fmaf(qs[l + k][c], dwk[k], s);
    dws[l][c] = s;
  }
  __syncthreads();

  // per-head pointwise mix: pw[l][o] = sum_i dws[l][i] * pw_w[h][o][i]
  // thread owns o = c, 16 l's. dws reads are wave-uniform -> broadcast.
  float accl[16];
#pragma unroll
  for (int i = 0; i < 16; ++i) accl[i] = 0.f;
  for (int i = 0; i < 64; ++i) {
    const float wv = pwws[i][c];
#pragma unroll
    for (int l2 = 0; l2 < 16; ++l2)
      accl[l2] = fmaf(dws[lset + l2][i], wv, accl[l2]);
  }
  const float pb = pw_b[d0 + c];
  __syncthreads();   // everyone done reading dws before we overwrite with ca
#pragma unroll
  for (int l2 = 0; l2 < 16; ++l2) {
    dws[lset + l2][c] = (accl[l2] + pb) * qs[lset + l2 + NPAD][c];
  }
  __syncthreads();

  // kern[l][k] = ca[l][:] . ak_w[h][k][:] + ak_b
  {
    const int l  = t & 63;
    const int kg = t >> 6;
    for (int k = kg; k < NK; k += 4) {
      float s = ak_b[h * NK + k];
      const float* aw = &ak_w[(size_t)(h * NK + k) * NIPG];
      for (int i = 0; i < 64; ++i) s = fmaf(dws[l][i], aw[i], s);
      ks[l][k] = s;
    }
  }
  __syncthreads();

  // softmax over k, write weights
  if (t < 64) {
    const int l = t;
    float m = ks[l][0];
#pragma unroll
    for (int k = 1; k < NK; ++k) m = fmaxf(m, ks[l][k]);
    float e[NK];
    float sum = 0.f;
#pragma unroll
    for (int k = 0; k < NK; ++k) { e[k] = expf(ks[l][k] - m); sum += e[k]; }
    const float inv = 1.f / sum;
    float* wp = &wout[(((size_t)(b * NL + l0 + l)) * NH + h) * NK];
#pragma unroll
    for (int k = 0; k < NK; ++k) wp[k] = e[k] * inv;
  }
}

// ---------------------------------------------------------------------------
// Kernel 3: out[b,l,d] = sum_k w[b,l,h(d),k] * v[b, l+k-4, d]  (zero pad)
// ---------------------------------------------------------------------------
__global__ __launch_bounds__(256) void sdconv_out(const float* __restrict__ v,
                                                  const float* __restrict__ w,
                                                  float* __restrict__ out) {
  const int b = blockIdx.z;
  const int l = blockIdx.y;
  const int d = blockIdx.x * 256 + threadIdx.x;
  const int h = d >> 6;
  const float* wp = &w[(((size_t)(b * NL + l)) * NH + h) * NK];
  float acc = 0.f;
#pragma unroll
  for (int k = 0; k < NK; ++k) {
    const int ls = l + k - NPAD;
    if (ls >= 0 && ls < NL)
      acc = fmaf(wp[k], v[((size_t)(b * NL + ls)) * ND + d], acc);
  }
  out[((size_t)(b * NL + l)) * ND + d] = acc;
}

// ---------------------------------------------------------------------------
extern "C" void kernel_launch(void* const* d_in, const int* in_sizes, int n_in,
                              void* d_out, int out_size, void* d_ws, size_t ws_size,
                              hipStream_t stream) {
  const float* query = (const float*)d_in[0];
  const float* dw_w  = (const float*)d_in[1];
  const float* pw_w  = (const float*)d_in[2];
  const float* pw_b  = (const float*)d_in[3];
  const float* ak_w  = (const float*)d_in[4];
  const float* ak_b  = (const float*)d_in[5];
  const float* pt_w  = (const float*)d_in[6];
  const float* pt_b  = (const float*)d_in[7];
  float* out = (float*)d_out;

  float* v = (float*)d_ws;                          // (B*L, D) fp32: 25.2 MB
  float* w = v + (size_t)NB * NL * ND;              // (B,L,H,K) fp32: 3.5 MB

  dim3 g1(NB * NL / 64, ND / 64, 1);
  gemm_v<<<g1, 256, 0, stream>>>(query, pt_w, pt_b, v);

  dim3 g2(NL / 64, NH, NB);
  attn_w<<<g2, 256, 0, stream>>>(query, dw_w, pw_w, pw_b, ak_w, ak_b, w);

  dim3 g3(ND / 256, NL, NB);
  sdconv_out<<<g3, 256, 0, stream>>>(v, w, out);
}

// Round 2
// 212.186 us; speedup vs baseline: 2.5538x; 2.5538x over previous
//
#include <hip/hip_runtime.h>
#include <math.h>

#define NB 4
#define NL 2048
#define ND 768
#define NH 12
#define NK 9
#define NIPG 64
#define NPAD 4

typedef __attribute__((ext_vector_type(8))) short s16x8;
typedef __attribute__((ext_vector_type(4))) float f32x4;

__device__ __forceinline__ unsigned short f2bf(float f) {
  unsigned int u = __float_as_uint(f);
  unsigned int r = (u + 0x7FFFu + ((u >> 16) & 1u)) >> 16;
  return (unsigned short)r;
}

__device__ __forceinline__ void gload16(const void* g, void* l) {
  __builtin_amdgcn_global_load_lds((const __attribute__((address_space(1))) void*)g,
                                   (__attribute__((address_space(3))) void*)l,
                                   16, 0, 0);
}

// ---------------------------------------------------------------------------
// Kernel 0: fp32 -> bf16 convert (RNE), vectorized float4 -> ushort4
// ---------------------------------------------------------------------------
__global__ __launch_bounds__(256) void f32_to_bf16(const float* __restrict__ src,
                                                   unsigned short* __restrict__ dst,
                                                   int n4) {
  int i = blockIdx.x * 256 + threadIdx.x;
  const int stride = gridDim.x * 256;
  for (; i < n4; i += stride) {
    float4 f = ((const float4*)src)[i];
    ushort4 o;
    o.x = f2bf(f.x); o.y = f2bf(f.y); o.z = f2bf(f.z); o.w = f2bf(f.w);
    ((ushort4*)dst)[i] = o;
  }
}

// ---------------------------------------------------------------------------
// Kernel 1: v = qb . ptb^T + pt_b   (bf16 MFMA, fp32 out)
// M=8192, N=768, K=768. Both operands K-contiguous (B^T layout).
// m97 structure: 128x128 tile, BK=32, 4 waves, 4x4 frags of 16x16x32,
// global_load_lds width=16 into linear LDS, 2 barriers per K-step.
// ---------------------------------------------------------------------------
__global__ __launch_bounds__(256) void gemm_v(const unsigned short* __restrict__ qb,
                                              const unsigned short* __restrict__ ptb,
                                              const float* __restrict__ bias,
                                              float* __restrict__ C) {
  __shared__ unsigned char lds[16384];   // As: [128][32] bf16 (8KB) | Bs: same
  const int t = threadIdx.x;
  const int m0 = blockIdx.x * 128;
  const int n0 = blockIdx.y * 128;
  const int lane = t & 63;
  const int wv = t >> 6;
  const int wr = wv >> 1, wc = wv & 1;   // wave -> 64x64 quadrant

  // staging addresses: LDS byte off = t*16 (+4096 for second half)
  const int soff = t * 16;
  const int sr = soff >> 6;              // row 0..63 within tile
  const int scb = soff & 63;             // byte col within 64B row
  const unsigned char* gA0 = (const unsigned char*)qb + (size_t)(m0 + sr) * (ND * 2) + scb;
  const unsigned char* gA1 = gA0 + (size_t)64 * (ND * 2);
  const unsigned char* gB0 = (const unsigned char*)ptb + (size_t)(n0 + sr) * (ND * 2) + scb;
  const unsigned char* gB1 = gB0 + (size_t)64 * (ND * 2);
  unsigned char* lA0 = &lds[soff];
  unsigned char* lA1 = lA0 + 4096;
  unsigned char* lB0 = &lds[8192 + soff];
  unsigned char* lB1 = lB0 + 4096;

  // fragment LDS byte offsets: row*(32 bf16)*2 + k0*2, k0=(lane>>4)*8
  int aoff[4], boff[4];
#pragma unroll
  for (int m = 0; m < 4; ++m)
    aoff[m] = ((wr * 64 + m * 16 + (lane & 15)) * 32 + (lane >> 4) * 8) * 2;
#pragma unroll
  for (int n = 0; n < 4; ++n)
    boff[n] = 8192 + ((wc * 64 + n * 16 + (lane & 15)) * 32 + (lane >> 4) * 8) * 2;

  f32x4 acc[4][4] = {};

  for (int kt = 0; kt < ND / 32; ++kt) {
    const int kb = kt * 64;              // byte advance along K
    gload16(gA0 + kb, lA0);
    gload16(gA1 + kb, lA1);
    gload16(gB0 + kb, lB0);
    gload16(gB1 + kb, lB1);
    __syncthreads();                     // vmcnt(0) drain: tile ready
    s16x8 av[4], bv[4];
#pragma unroll
    for (int m = 0; m < 4; ++m) av[m] = *(const s16x8*)&lds[aoff[m]];
#pragma unroll
    for (int n = 0; n < 4; ++n) bv[n] = *(const s16x8*)&lds[boff[n]];
#pragma unroll
    for (int m = 0; m < 4; ++m)
#pragma unroll
      for (int n = 0; n < 4; ++n)
        acc[m][n] = __builtin_amdgcn_mfma_f32_16x16x32_bf16(av[m], bv[n], acc[m][n], 0, 0, 0);
    __syncthreads();                     // all reads done before next overwrite
  }

  // epilogue: C/D map col=lane&15, row=(lane>>4)*4+j  [m89-verified]
#pragma unroll
  for (int m = 0; m < 4; ++m) {
#pragma unroll
    for (int n = 0; n < 4; ++n) {
      const int row = m0 + wr * 64 + m * 16 + (lane >> 4) * 4;
      const int col = n0 + wc * 64 + n * 16 + (lane & 15);
      const float bb = bias[col];
#pragma unroll
      for (int j = 0; j < 4; ++j)
        C[(size_t)(row + j) * ND + col] = acc[m][n][j] + bb;
    }
  }
}

// ---------------------------------------------------------------------------
// Kernel 2: dynamic conv weights (unchanged from round 1 — known correct).
// ---------------------------------------------------------------------------
__global__ __launch_bounds__(256) void attn_w(const float* __restrict__ q,
                                              const float* __restrict__ dw_w,
                                              const float* __restrict__ pw_w,
                                              const float* __restrict__ pw_b,
                                              const float* __restrict__ ak_w,
                                              const float* __restrict__ ak_b,
                                              float* __restrict__ wout) {
  __shared__ float qs[72][64];
  __shared__ float dws[64][65];
  __shared__ float pwws[64][64];
  __shared__ float ks[64][13];
  const int l0 = blockIdx.x * 64;
  const int h  = blockIdx.y;
  const int b  = blockIdx.z;
  const int d0 = h * NIPG;
  const int t  = threadIdx.x;
  const int c  = t & 63;
  const int rr = t >> 6;

  for (int r = rr; r < 72; r += 4) {
    int l = l0 - NPAD + r;
    qs[r][c] = (l >= 0 && l < NL) ? q[((size_t)(b * NL + l)) * ND + d0 + c] : 0.f;
  }
  for (int i = rr; i < 64; i += 4) {
    pwws[i][c] = pw_w[(size_t)(h * NIPG + c) * NIPG + i];
  }
  float dwk[NK];
#pragma unroll
  for (int k = 0; k < NK; ++k) dwk[k] = dw_w[(size_t)(d0 + c) * NK + k];
  __syncthreads();

  const int lset = rr * 16;
#pragma unroll
  for (int l2 = 0; l2 < 16; ++l2) {
    const int l = lset + l2;
    float s = 0.f;
#pragma unroll
    for (int k = 0; k < NK; ++k) s = fmaf(qs[l + k][c], dwk[k], s);
    dws[l][c] = s;
  }
  __syncthreads();

  float accl[16];
#pragma unroll
  for (int i = 0; i < 16; ++i) accl[i] = 0.f;
  for (int i = 0; i < 64; ++i) {
    const float wv = pwws[i][c];
#pragma unroll
    for (int l2 = 0; l2 < 16; ++l2)
      accl[l2] = fmaf(dws[lset + l2][i], wv, accl[l2]);
  }
  const float pb = pw_b[d0 + c];
  __syncthreads();
#pragma unroll
  for (int l2 = 0; l2 < 16; ++l2) {
    dws[lset + l2][c] = (accl[l2] + pb) * qs[lset + l2 + NPAD][c];
  }
  __syncthreads();

  {
    const int l  = t & 63;
    const int kg = t >> 6;
    for (int k = kg; k < NK; k += 4) {
      float s = ak_b[h * NK + k];
      const float* aw = &ak_w[(size_t)(h * NK + k) * NIPG];
      for (int i = 0; i < 64; ++i) s = fmaf(dws[l][i], aw[i], s);
      ks[l][k] = s;
    }
  }
  __syncthreads();

  if (t < 64) {
    const int l = t;
    float m = ks[l][0];
#pragma unroll
    for (int k = 1; k < NK; ++k) m = fmaxf(m, ks[l][k]);
    float e[NK];
    float sum = 0.f;
#pragma unroll
    for (int k = 0; k < NK; ++k) { e[k] = expf(ks[l][k] - m); sum += e[k]; }
    const float inv = 1.f / sum;
    float* wp = &wout[(((size_t)(b * NL + l0 + l)) * NH + h) * NK];
#pragma unroll
    for (int k = 0; k < NK; ++k) wp[k] = e[k] * inv;
  }
}

// ---------------------------------------------------------------------------
// Kernel 3: out[b,l,d] = sum_k w[b,l,h(d),k] * v[b, l+k-4, d]  (unchanged)
// ---------------------------------------------------------------------------
__global__ __launch_bounds__(256) void sdconv_out(const float* __restrict__ v,
                                                  const float* __restrict__ w,
                                                  float* __restrict__ out) {
  const int b = blockIdx.z;
  const int l = blockIdx.y;
  const int d = blockIdx.x * 256 + threadIdx.x;
  const int h = d >> 6;
  const float* wp = &w[(((size_t)(b * NL + l)) * NH + h) * NK];
  float acc = 0.f;
#pragma unroll
  for (int k = 0; k < NK; ++k) {
    const int ls = l + k - NPAD;
    if (ls >= 0 && ls < NL)
      acc = fmaf(wp[k], v[((size_t)(b * NL + ls)) * ND + d], acc);
  }
  out[((size_t)(b * NL + l)) * ND + d] = acc;
}

// ---------------------------------------------------------------------------
extern "C" void kernel_launch(void* const* d_in, const int* in_sizes, int n_in,
                              void* d_out, int out_size, void* d_ws, size_t ws_size,
                              hipStream_t stream) {
  const float* query = (const float*)d_in[0];
  const float* dw_w  = (const float*)d_in[1];
  const float* pw_w  = (const float*)d_in[2];
  const float* pw_b  = (const float*)d_in[3];
  const float* ak_w  = (const float*)d_in[4];
  const float* ak_b  = (const float*)d_in[5];
  const float* pt_w  = (const float*)d_in[6];
  const float* pt_b  = (const float*)d_in[7];
  float* out = (float*)d_out;

  // workspace layout
  float* v = (float*)d_ws;                               // 8192*768 f32 = 25.2MB
  float* w = v + (size_t)NB * NL * ND;                   // B*L*H*K f32 = 3.5MB
  unsigned short* qb  = (unsigned short*)(w + (size_t)NB * NL * NH * NK); // 12.6MB
  unsigned short* ptb = qb + (size_t)NB * NL * ND;       // 1.2MB

  const int nq4 = NB * NL * ND / 4;
  const int np4 = ND * ND / 4;
  f32_to_bf16<<<1024, 256, 0, stream>>>(query, qb, nq4);
  f32_to_bf16<<<256, 256, 0, stream>>>(pt_w, ptb, np4);

  dim3 g1(NB * NL / 128, ND / 128, 1);
  gemm_v<<<g1, 256, 0, stream>>>(qb, ptb, pt_b, v);

  dim3 g2(NL / 64, NH, NB);
  attn_w<<<g2, 256, 0, stream>>>(query, dw_w, pw_w, pw_b, ak_w, ak_b, w);

  dim3 g3(ND / 256, NL, NB);
  sdconv_out<<<g3, 256, 0, stream>>>(v, w, out);
}

// Round 3
// 147.861 us; speedup vs baseline: 3.6647x; 1.4350x over previous
//
#include <hip/hip_runtime.h>
#include <math.h>

#define NB 4
#define NL 2048
#define ND 768
#define NH 12
#define NK 9
#define NIPG 64
#define NPAD 4
#define LT 16

typedef __attribute__((ext_vector_type(8))) short s16x8;
typedef __attribute__((ext_vector_type(4))) float f32x4;

__device__ __forceinline__ unsigned short f2bf(float f) {
  unsigned int u = __float_as_uint(f);
  unsigned int r = (u + 0x7FFFu + ((u >> 16) & 1u)) >> 16;
  return (unsigned short)r;
}
__device__ __forceinline__ float bf2f(unsigned short s) {
  return __uint_as_float(((unsigned int)s) << 16);
}

__device__ __forceinline__ void gload16(const void* g, void* l) {
  __builtin_amdgcn_global_load_lds((const __attribute__((address_space(1))) void*)g,
                                   (__attribute__((address_space(3))) void*)l,
                                   16, 0, 0);
}

// ---------------------------------------------------------------------------
// Kernel 0: fp32 -> bf16 convert (RNE), vectorized
// ---------------------------------------------------------------------------
__global__ __launch_bounds__(256) void f32_to_bf16(const float* __restrict__ src,
                                                   unsigned short* __restrict__ dst,
                                                   int n4) {
  int i = blockIdx.x * 256 + threadIdx.x;
  const int stride = gridDim.x * 256;
  for (; i < n4; i += stride) {
    float4 f = ((const float4*)src)[i];
    ushort4 o;
    o.x = f2bf(f.x); o.y = f2bf(f.y); o.z = f2bf(f.z); o.w = f2bf(f.w);
    ((ushort4*)dst)[i] = o;
  }
}

// ---------------------------------------------------------------------------
// Kernel 0b: weight prep. pwb[h][o][i] = bf16(pw_w); akp[h][k][i] (k padded
// to 16 with zeros) = bf16(ak_w).
// ---------------------------------------------------------------------------
__global__ __launch_bounds__(256) void prep_w(const float* __restrict__ pw_w,
                                              const float* __restrict__ ak_w,
                                              unsigned short* __restrict__ pwb,
                                              unsigned short* __restrict__ akp) {
  const int t = blockIdx.x * 256 + threadIdx.x;
  if (t < NH * NIPG * NIPG) pwb[t] = f2bf(pw_w[t]);
  if (t < NH * 16 * NIPG) {
    const int h = t >> 10;          // /1024
    const int r = t & 1023;
    const int k = r >> 6;
    const int i = r & 63;
    akp[t] = (k < NK) ? f2bf(ak_w[((size_t)h * NK + k) * NIPG + i]) : (unsigned short)0;
  }
}

// ---------------------------------------------------------------------------
// Kernel 1: v = qb . ptb^T + pt_b  (bf16 MFMA, bf16 out)
// m97 structure: 128x128 tile, BK=32, 4 waves, 4x4 frags of 16x16x32.
// ---------------------------------------------------------------------------
__global__ __launch_bounds__(256) void gemm_v(const unsigned short* __restrict__ qb,
                                              const unsigned short* __restrict__ ptb,
                                              const float* __restrict__ bias,
                                              unsigned short* __restrict__ vb) {
  __shared__ unsigned char lds[16384];
  const int t = threadIdx.x;
  const int m0 = blockIdx.x * 128;
  const int n0 = blockIdx.y * 128;
  const int lane = t & 63;
  const int wv = t >> 6;
  const int wr = wv >> 1, wc = wv & 1;

  const int soff = t * 16;
  const int sr = soff >> 6;
  const int scb = soff & 63;
  const unsigned char* gA0 = (const unsigned char*)qb + (size_t)(m0 + sr) * (ND * 2) + scb;
  const unsigned char* gA1 = gA0 + (size_t)64 * (ND * 2);
  const unsigned char* gB0 = (const unsigned char*)ptb + (size_t)(n0 + sr) * (ND * 2) + scb;
  const unsigned char* gB1 = gB0 + (size_t)64 * (ND * 2);
  unsigned char* lA0 = &lds[soff];
  unsigned char* lA1 = lA0 + 4096;
  unsigned char* lB0 = &lds[8192 + soff];
  unsigned char* lB1 = lB0 + 4096;

  int aoff[4], boff[4];
#pragma unroll
  for (int m = 0; m < 4; ++m)
    aoff[m] = ((wr * 64 + m * 16 + (lane & 15)) * 32 + (lane >> 4) * 8) * 2;
#pragma unroll
  for (int n = 0; n < 4; ++n)
    boff[n] = 8192 + ((wc * 64 + n * 16 + (lane & 15)) * 32 + (lane >> 4) * 8) * 2;

  f32x4 acc[4][4] = {};

  for (int kt = 0; kt < ND / 32; ++kt) {
    const int kb = kt * 64;
    gload16(gA0 + kb, lA0);
    gload16(gA1 + kb, lA1);
    gload16(gB0 + kb, lB0);
    gload16(gB1 + kb, lB1);
    __syncthreads();
    s16x8 av[4], bv[4];
#pragma unroll
    for (int m = 0; m < 4; ++m) av[m] = *(const s16x8*)&lds[aoff[m]];
#pragma unroll
    for (int n = 0; n < 4; ++n) bv[n] = *(const s16x8*)&lds[boff[n]];
#pragma unroll
    for (int m = 0; m < 4; ++m)
#pragma unroll
      for (int n = 0; n < 4; ++n)
        acc[m][n] = __builtin_amdgcn_mfma_f32_16x16x32_bf16(av[m], bv[n], acc[m][n], 0, 0, 0);
    __syncthreads();
  }

#pragma unroll
  for (int m = 0; m < 4; ++m) {
#pragma unroll
    for (int n = 0; n < 4; ++n) {
      const int row = m0 + wr * 64 + m * 16 + (lane >> 4) * 4;
      const int col = n0 + wc * 64 + n * 16 + (lane & 15);
      const float bb = bias[col];
#pragma unroll
      for (int j = 0; j < 4; ++j)
        vb[(size_t)(row + j) * ND + col] = f2bf(acc[m][n][j] + bb);
    }
  }
}

// ---------------------------------------------------------------------------
// Kernel 2: dynamic conv weights, MFMA version.
// Block = (b, h, 64 l's), 4 waves; wave w owns l-strip [16w, 16w+16).
// depthwise (fp32 VALU) -> ab LDS bf16 (XOR-swizzled) -> MFMA pw-mix
// (B-frags from global pwb) -> ca=(pw+b)*q -> ab -> MFMA ak (B from akp)
// -> shfl softmax over k -> wout.
// ---------------------------------------------------------------------------
__global__ __launch_bounds__(256) void attn_w(const float* __restrict__ q,
                                              const float* __restrict__ dw_w,
                                              const unsigned short* __restrict__ pwb,
                                              const float* __restrict__ pw_b,
                                              const unsigned short* __restrict__ akp,
                                              const float* __restrict__ ak_b,
                                              float* __restrict__ wout) {
  __shared__ float qs[72][68];          // 19.6KB, stride 68 rotates banks by 4
  __shared__ unsigned char ab[8192];    // [64][64] bf16, byte ^= (row&7)<<4
  const int l0 = blockIdx.x * 64;
  const int h  = blockIdx.y;
  const int b  = blockIdx.z;
  const int d0 = h * NIPG;
  const int t  = threadIdx.x;
  const int lane = t & 63;
  const int wv = t >> 6;

  // stage q rows l0-4 .. l0+67 (float4 coalesced)
  {
    const int sl = t >> 4;
    const int sc = (t & 15) * 4;
    for (int r = sl; r < 72; r += 16) {
      const int l = l0 - NPAD + r;
      float4 val = make_float4(0.f, 0.f, 0.f, 0.f);
      if (l >= 0 && l < NL) val = *(const float4*)&q[((size_t)(b * NL + l)) * ND + d0 + sc];
      *(float4*)&qs[r][sc] = val;
    }
  }
  float dwk[NK];
#pragma unroll
  for (int k = 0; k < NK; ++k) dwk[k] = dw_w[(size_t)(d0 + lane) * NK + k];
  __syncthreads();

  // depthwise conv; write bf16 swizzled
  const int lset = wv * 16;
#pragma unroll
  for (int l2 = 0; l2 < 16; ++l2) {
    const int l = lset + l2;
    float s = 0.f;
#pragma unroll
    for (int k = 0; k < NK; ++k) s = fmaf(qs[l + k][lane], dwk[k], s);
    const int byte = ((l * 64 + lane) * 2) ^ ((l & 7) << 4);
    *(unsigned short*)&ab[byte] = f2bf(s);
  }
  __syncthreads();

  const int fr = lane & 15;   // frag row (A) / col (B)
  const int fq = lane >> 4;   // k-quad

  // MFMA #1: pw[l][o] = dw[l][:] . pw_w[h][o][:]
  s16x8 av0, av1;
  {
    const int row = lset + fr;
    const int b0 = ((row * 64 + fq * 8) * 2)      ^ ((row & 7) << 4);
    const int b1 = ((row * 64 + 32 + fq * 8) * 2) ^ ((row & 7) << 4);
    av0 = *(const s16x8*)&ab[b0];
    av1 = *(const s16x8*)&ab[b1];
  }
  const unsigned short* pwh = pwb + (size_t)h * NIPG * NIPG;
  f32x4 accp[4];
#pragma unroll
  for (int n = 0; n < 4; ++n) {
    accp[n] = (f32x4){0.f, 0.f, 0.f, 0.f};
    const int o = n * 16 + fr;
    s16x8 bv0 = *(const s16x8*)&pwh[o * 64 + fq * 8];
    s16x8 bv1 = *(const s16x8*)&pwh[o * 64 + 32 + fq * 8];
    accp[n] = __builtin_amdgcn_mfma_f32_16x16x32_bf16(av0, bv0, accp[n], 0, 0, 0);
    accp[n] = __builtin_amdgcn_mfma_f32_16x16x32_bf16(av1, bv1, accp[n], 0, 0, 0);
  }
  __syncthreads();   // av reads complete everywhere before ab overwrite

  // ca = (pw + pw_b) * q -> ab (bf16 swizzled). C/D: row=(fq*4+j), col=o.
#pragma unroll
  for (int n = 0; n < 4; ++n) {
    const int o = n * 16 + fr;
    const float pb = pw_b[d0 + o];
#pragma unroll
    for (int j = 0; j < 4; ++j) {
      const int row = lset + fq * 4 + j;
      const float ca = (accp[n][j] + pb) * qs[row + NPAD][o];
      const int byte = ((row * 64 + o) * 2) ^ ((row & 7) << 4);
      *(unsigned short*)&ab[byte] = f2bf(ca);
    }
  }
  __syncthreads();

  // MFMA #2: kern[l][k] = ca[l][:] . ak_w[h][k][:]  (k padded to 16)
  f32x4 acck = (f32x4){0.f, 0.f, 0.f, 0.f};
  {
    const int row = lset + fr;
    const int b0 = ((row * 64 + fq * 8) * 2)      ^ ((row & 7) << 4);
    const int b1 = ((row * 64 + 32 + fq * 8) * 2) ^ ((row & 7) << 4);
    s16x8 a0 = *(const s16x8*)&ab[b0];
    s16x8 a1 = *(const s16x8*)&ab[b1];
    const unsigned short* akh = akp + (size_t)h * 16 * NIPG;
    s16x8 b0v = *(const s16x8*)&akh[fr * 64 + fq * 8];
    s16x8 b1v = *(const s16x8*)&akh[fr * 64 + 32 + fq * 8];
    acck = __builtin_amdgcn_mfma_f32_16x16x32_bf16(a0, b0v, acck, 0, 0, 0);
    acck = __builtin_amdgcn_mfma_f32_16x16x32_bf16(a1, b1v, acck, 0, 0, 0);
  }

  // + ak_b; softmax over k (across the 16-lane col group); write weights
  const bool kvalid = fr < NK;
  const float akbv = kvalid ? ak_b[h * NK + fr] : 0.f;
#pragma unroll
  for (int j = 0; j < 4; ++j) {
    float val = acck[j] + akbv;
    float mv = kvalid ? val : -3.4e38f;
#pragma unroll
    for (int mm = 1; mm < 16; mm <<= 1) mv = fmaxf(mv, __shfl_xor(mv, mm));
    const float e = kvalid ? __expf(val - mv) : 0.f;
    float ssum = e;
#pragma unroll
    for (int mm = 1; mm < 16; mm <<= 1) ssum += __shfl_xor(ssum, mm);
    if (kvalid) {
      const int row = l0 + lset + fq * 4 + j;
      wout[(((size_t)(b * NL + row)) * NH + h) * NK + fr] = e / ssum;
    }
  }
}

// ---------------------------------------------------------------------------
// Kernel 3: out[b,l,d] = sum_k w[b,l,h,k] * v[b,l+k-4,d].  Rolling window:
// each thread owns 4 d's, slides over LT l's, 1 new v row load per step.
// ---------------------------------------------------------------------------
__global__ __launch_bounds__(192) void sdconv_out(const unsigned short* __restrict__ v,
                                                  const float* __restrict__ w,
                                                  float* __restrict__ out) {
  const int b  = blockIdx.y;
  const int l0 = blockIdx.x * LT;
  const int t  = threadIdx.x;          // 0..191
  const int d  = t * 4;
  const int h  = t >> 4;               // d/64
  const size_t vbase = (size_t)b * NL * ND + d;

  float4 win[NK];
#pragma unroll
  for (int k = 0; k < NK; ++k) {
    const int r = l0 - NPAD + k;
    if (r >= 0 && r < NL) {
      ushort4 u = *(const ushort4*)&v[vbase + (size_t)r * ND];
      win[k] = make_float4(bf2f(u.x), bf2f(u.y), bf2f(u.z), bf2f(u.w));
    } else {
      win[k] = make_float4(0.f, 0.f, 0.f, 0.f);
    }
  }
#pragma unroll
  for (int l2 = 0; l2 < LT; ++l2) {
    const int l = l0 + l2;
    const float* wp = &w[(((size_t)(b * NL + l)) * NH + h) * NK];
    float4 acc = make_float4(0.f, 0.f, 0.f, 0.f);
#pragma unroll
    for (int k = 0; k < NK; ++k) {
      const float wk = wp[k];
      acc.x = fmaf(wk, win[k].x, acc.x);
      acc.y = fmaf(wk, win[k].y, acc.y);
      acc.z = fmaf(wk, win[k].z, acc.z);
      acc.w = fmaf(wk, win[k].w, acc.w);
    }
    *(float4*)&out[(size_t)(b * NL + l) * ND + d] = acc;
#pragma unroll
    for (int k = 0; k < NK - 1; ++k) win[k] = win[k + 1];
    const int rn = l + NPAD + 1;
    if (rn < NL) {
      ushort4 u = *(const ushort4*)&v[vbase + (size_t)rn * ND];
      win[NK - 1] = make_float4(bf2f(u.x), bf2f(u.y), bf2f(u.z), bf2f(u.w));
    } else {
      win[NK - 1] = make_float4(0.f, 0.f, 0.f, 0.f);
    }
  }
}

// ---------------------------------------------------------------------------
extern "C" void kernel_launch(void* const* d_in, const int* in_sizes, int n_in,
                              void* d_out, int out_size, void* d_ws, size_t ws_size,
                              hipStream_t stream) {
  const float* query = (const float*)d_in[0];
  const float* dw_w  = (const float*)d_in[1];
  const float* pw_w  = (const float*)d_in[2];
  const float* pw_b  = (const float*)d_in[3];
  const float* ak_w  = (const float*)d_in[4];
  const float* ak_b  = (const float*)d_in[5];
  const float* pt_w  = (const float*)d_in[6];
  const float* pt_b  = (const float*)d_in[7];
  float* out = (float*)d_out;

  // workspace layout (30.0 MB total)
  unsigned short* v = (unsigned short*)d_ws;                      // 12.58MB bf16
  float* w = (float*)(v + (size_t)NB * NL * ND);                  // 3.54MB f32
  unsigned short* qb  = (unsigned short*)(w + (size_t)NB * NL * NH * NK); // 12.58MB
  unsigned short* ptb = qb + (size_t)NB * NL * ND;                // 1.18MB
  unsigned short* pwb = ptb + (size_t)ND * ND;                    // 98KB
  unsigned short* akp = pwb + (size_t)NH * NIPG * NIPG;           // 24.6KB

  f32_to_bf16<<<1024, 256, 0, stream>>>(query, qb, NB * NL * ND / 4);
  f32_to_bf16<<<256, 256, 0, stream>>>(pt_w, ptb, ND * ND / 4);
  prep_w<<<192, 256, 0, stream>>>(pw_w, ak_w, pwb, akp);

  dim3 g1(NB * NL / 128, ND / 128, 1);
  gemm_v<<<g1, 256, 0, stream>>>(qb, ptb, pt_b, v);

  dim3 g2(NL / 64, NH, NB);
  attn_w<<<g2, 256, 0, stream>>>(query, dw_w, pwb, pw_b, akp, ak_b, w);

  dim3 g3(NL / LT, NB, 1);
  sdconv_out<<<g3, 192, 0, stream>>>(v, w, out);
}